// Round 1
// baseline (229.512 us; speedup 1.0000x reference)
//
#include <hip/hip_runtime.h>

// Problem constants (from reference):
//   B=16, S=4096, D_MODEL=512, PE_DIM=256, N_DIM_DIVIDE=2
// out[b,s,d] = x[b,s,d] + pe[s, d%256] + (s < L_b ? pe[L_b-1-s, 255-(d%256)] : 0)
// L_b = sum_s (mask[b,s] == 0)

#define B_SZ   16
#define S_LEN  4096
#define D_MOD  512
#define PE_D   256

// ---------------- kernel 1: per-batch lengths ----------------
// 16 blocks x 256 threads; each batch row is 4096 ints = 1024 int4.
__global__ __launch_bounds__(256) void lengths_kernel(
    const int* __restrict__ mask, int* __restrict__ lengths)
{
    const int b   = blockIdx.x;
    const int tid = threadIdx.x;
    const int4* m4 = reinterpret_cast<const int4*>(mask + (size_t)b * S_LEN);

    int cnt = 0;
    #pragma unroll
    for (int i = 0; i < (S_LEN / 4) / 256; ++i) {
        int4 v = m4[tid + i * 256];
        cnt += (v.x == 0) + (v.y == 0) + (v.z == 0) + (v.w == 0);
    }
    // wave (64-lane) reduction
    #pragma unroll
    for (int off = 32; off > 0; off >>= 1)
        cnt += __shfl_down(cnt, off, 64);

    __shared__ int wsum[4];
    const int lane = tid & 63;
    const int wave = tid >> 6;
    if (lane == 0) wsum[wave] = cnt;
    __syncthreads();
    if (tid == 0)
        lengths[b] = wsum[0] + wsum[1] + wsum[2] + wsum[3];
}

// ---------------- kernel 2: fused add ----------------
// 256 threads/block, 2 rows (b,s) per block, one float4 per thread.
// D=512 -> 128 float4 per row; tid>>7 selects row, tid&127 selects float4.
__global__ __launch_bounds__(256) void pe_add_kernel(
    const float* __restrict__ x, const float* __restrict__ pe,
    const int* __restrict__ lengths, float* __restrict__ out)
{
    const int tid = threadIdx.x;
    const long row = (long)blockIdx.x * 2 + (tid >> 7);   // [0, B*S)
    const int d4   = tid & 127;                           // float4 idx in row
    const int b    = (int)(row >> 12);                    // S = 4096 = 2^12
    const int s    = (int)(row & (S_LEN - 1));
    const int d    = d4 << 2;                             // [0, 512), mult of 4
    const int d256 = d & (PE_D - 1);                      // mult of 4

    const long off = row * D_MOD + d;
    const float4 xv = *reinterpret_cast<const float4*>(x + off);
    const float4 pv = *reinterpret_cast<const float4*>(pe + (size_t)s * PE_D + d256);

    float4 r = make_float4(0.f, 0.f, 0.f, 0.f);
    const int L = lengths[b];          // wave-uniform
    if (s < L) {                       // wave-uniform branch
        const int idx = L - 1 - s;     // >= 0 when s < L
        // need pe[idx, 255 - (d256+j)] for j=0..3 -> reversed float4 at 252-d256
        const float4 rv = *reinterpret_cast<const float4*>(
            pe + (size_t)idx * PE_D + (252 - d256));
        r = make_float4(rv.w, rv.z, rv.y, rv.x);
    }

    // match reference association: (x + add_rev) + base
    float4 o;
    o.x = (xv.x + r.x) + pv.x;
    o.y = (xv.y + r.y) + pv.y;
    o.z = (xv.z + r.z) + pv.z;
    o.w = (xv.w + r.w) + pv.w;
    *reinterpret_cast<float4*>(out + off) = o;
}

extern "C" void kernel_launch(void* const* d_in, const int* in_sizes, int n_in,
                              void* d_out, int out_size, void* d_ws, size_t ws_size,
                              hipStream_t stream)
{
    const float* x    = (const float*)d_in[0];   // (16, 4096, 512) fp32
    const int*   mask = (const int*)d_in[1];     // (16, 4096) int32
    const float* pe   = (const float*)d_in[2];   // (5000, 256) fp32
    float* out        = (float*)d_out;
    int*   lengths    = (int*)d_ws;              // 16 ints of scratch

    lengths_kernel<<<B_SZ, 256, 0, stream>>>(mask, lengths);

    const int n_rows = B_SZ * S_LEN;             // 65536
    pe_add_kernel<<<n_rows / 2, 256, 0, stream>>>(x, pe, lengths, out);
}

// Round 2
// 226.317 us; speedup vs baseline: 1.0141x; 1.0141x over previous
//
#include <hip/hip_runtime.h>

// Problem constants (from reference):
//   B=16, S=4096, D_MODEL=512, PE_DIM=256, N_DIM_DIVIDE=2
// out[b,s,d] = x[b,s,d] + pe[s, d%256] + (s < L_b ? pe[L_b-1-s, 255-(d%256)] : 0)
// L_b = sum_s (mask[b,s] == 0)
//
// Key structure: d and d+256 use IDENTICAL pe values -> one wave (64 lanes x
// float4 = 256 floats) loads each pe row once and covers a full 512-float
// output row. x/out are streaming (zero reuse) -> nontemporal; pe is hot
// (5 MB, L2/L3-resident) -> cached loads.

#define B_SZ   16
#define S_LEN  4096
#define D_MOD  512
#define PE_D   256

typedef float v4f __attribute__((ext_vector_type(4)));

// ---------------- kernel 1: per-batch lengths ----------------
// 16 blocks x 256 threads; each batch row is 4096 ints = 1024 int4.
__global__ __launch_bounds__(256) void lengths_kernel(
    const int* __restrict__ mask, int* __restrict__ lengths)
{
    const int b   = blockIdx.x;
    const int tid = threadIdx.x;
    const int4* m4 = reinterpret_cast<const int4*>(mask + (size_t)b * S_LEN);

    int cnt = 0;
    #pragma unroll
    for (int i = 0; i < (S_LEN / 4) / 256; ++i) {
        int4 v = m4[tid + i * 256];
        cnt += (v.x == 0) + (v.y == 0) + (v.z == 0) + (v.w == 0);
    }
    #pragma unroll
    for (int off = 32; off > 0; off >>= 1)
        cnt += __shfl_down(cnt, off, 64);

    __shared__ int wsum[4];
    const int lane = tid & 63;
    const int wave = tid >> 6;
    if (lane == 0) wsum[wave] = cnt;
    __syncthreads();
    if (tid == 0)
        lengths[b] = wsum[0] + wsum[1] + wsum[2] + wsum[3];
}

// ---------------- kernel 2: fused add ----------------
// 256 threads/block = 4 waves; wave w handles row (blockIdx*4 + w).
// Lane l covers d = 4l (first half) and d = 4l + 256 (second half) with the
// SAME pe base/rev float4 -> 4 loads + 2 stores per 32 B of output.
__global__ __launch_bounds__(256) void pe_add_kernel(
    const float* __restrict__ x, const float* __restrict__ pe,
    const int* __restrict__ lengths, float* __restrict__ out)
{
    const int tid  = threadIdx.x;
    const int lane = tid & 63;
    const int wave = tid >> 6;
    const long row = (long)blockIdx.x * 4 + wave;       // [0, B*S)
    const int b    = (int)(row >> 12);                  // S = 4096 = 2^12
    const int s    = (int)(row & (S_LEN - 1));
    const int d    = lane << 2;                         // [0, 256), mult of 4

    const long off = row * D_MOD + d;
    const v4f xv0 = __builtin_nontemporal_load(
        reinterpret_cast<const v4f*>(x + off));
    const v4f xv1 = __builtin_nontemporal_load(
        reinterpret_cast<const v4f*>(x + off + PE_D));
    const v4f pv = *reinterpret_cast<const v4f*>(pe + (size_t)s * PE_D + d);

    v4f r = {0.f, 0.f, 0.f, 0.f};
    const int L = lengths[b];          // wave-uniform (whole wave same row)
    if (s < L) {                       // wave-uniform branch
        const int idx = L - 1 - s;     // in [0, 4095]
        // need pe[idx, 255-(d+j)] for j=0..3 -> reversed float4 at 252-d
        const v4f rv = *reinterpret_cast<const v4f*>(
            pe + (size_t)idx * PE_D + (252 - d));
        r = (v4f){rv.w, rv.z, rv.y, rv.x};
    }

    // match reference association: (x + add_rev) + base
    v4f o0 = (xv0 + r) + pv;
    v4f o1 = (xv1 + r) + pv;
    __builtin_nontemporal_store(o0, reinterpret_cast<v4f*>(out + off));
    __builtin_nontemporal_store(o1, reinterpret_cast<v4f*>(out + off + PE_D));
}

extern "C" void kernel_launch(void* const* d_in, const int* in_sizes, int n_in,
                              void* d_out, int out_size, void* d_ws, size_t ws_size,
                              hipStream_t stream)
{
    const float* x    = (const float*)d_in[0];   // (16, 4096, 512) fp32
    const int*   mask = (const int*)d_in[1];     // (16, 4096) int32
    const float* pe   = (const float*)d_in[2];   // (5000, 256) fp32
    float* out        = (float*)d_out;
    int*   lengths    = (int*)d_ws;              // 16 ints of scratch

    lengths_kernel<<<B_SZ, 256, 0, stream>>>(mask, lengths);

    const int n_rows = B_SZ * S_LEN;             // 65536
    pe_add_kernel<<<n_rows / 4, 256, 0, stream>>>(x, pe, lengths, out);
}